// Round 1
// baseline (1354.858 us; speedup 1.0000x reference)
//
#include <hip/hip_runtime.h>
#include <cstdint>
#include <cstddef>

// ---------------------------------------------------------------------------
// SparkFieldNet single step. Reproduces JAX threefry (partitionable mode,
// default since jax 0.4.30) bit-exactly for the sampling path.
// Outputs (all written as float32, concatenated): pos[256], W[8192*8192],
// s[8192], M[8192], energy[256], age[256].
// ---------------------------------------------------------------------------

#define NN 8192
#define KK 256

__host__ __device__ inline void tf2x32(uint32_t k0, uint32_t k1, uint32_t x0, uint32_t x1,
                                       uint32_t& o0, uint32_t& o1) {
  uint32_t ks2 = k0 ^ k1 ^ 0x1BD11BDAu;
  x0 += k0; x1 += k1;
#define TFR(r) { x0 += x1; x1 = (x1 << (r)) | (x1 >> (32 - (r))); x1 ^= x0; }
  TFR(13) TFR(15) TFR(26) TFR(6)
  x0 += k1; x1 += ks2 + 1u;
  TFR(17) TFR(29) TFR(16) TFR(24)
  x0 += ks2; x1 += k0 + 2u;
  TFR(13) TFR(15) TFR(26) TFR(6)
  x0 += k0; x1 += k1 + 3u;
  TFR(17) TFR(29) TFR(16) TFR(24)
  x0 += k1; x1 += ks2 + 4u;
  TFR(13) TFR(15) TFR(26) TFR(6)
  x0 += ks2; x1 += k0 + 5u;
#undef TFR
  o0 = x0; o1 = x1;
}

__device__ __forceinline__ float u01f(uint32_t b) {
  // JAX uniform bits->float: (bits>>9)|0x3f800000 bitcast - 1.0f  in [0,1)
  return __uint_as_float((b >> 9) | 0x3f800000u) - 1.0f;
}

__device__ __forceinline__ float gumbelf(uint32_t b) {
  // u = max(tiny, f*(1-tiny)+tiny) == (f==0 ? tiny : f) in f32
  float f = u01f(b);
  float u = (f == 0.0f) ? 1.17549435e-38f : f;
  // -log(-log(u)) with each log rounded to f32 (f64 log => correctly rounded)
  float a = (float)log((double)u);     // < 0
  float c = (float)log((double)(-a));
  return -c;
}

// ---------------------------------------------------------------------------
// K1: y = W @ (0.95*s_in), and W_out = clip(W*0.999, -2, 2)   (one pass over W)
// ---------------------------------------------------------------------------
__global__ __launch_bounds__(256) void k_matvec(const float* __restrict__ W,
                                                const float* __restrict__ s_in,
                                                float* __restrict__ W_out,
                                                float* __restrict__ y) {
  int r = blockIdx.x, tid = threadIdx.x;
  const float4* Wr = (const float4*)(W + (size_t)r * NN);
  float4* Wo = (float4*)(W_out + (size_t)r * NN);
  const float4* S4 = (const float4*)s_in;
  float acc = 0.0f;
  for (int k = tid; k < NN / 4; k += 256) {
    float4 w = Wr[k];
    float4 sv = S4[k];
    acc += w.x * (0.95f * sv.x) + w.y * (0.95f * sv.y) +
           w.z * (0.95f * sv.z) + w.w * (0.95f * sv.w);
    float4 o;
    o.x = fminf(fmaxf(w.x * 0.999f, -2.0f), 2.0f);
    o.y = fminf(fmaxf(w.y * 0.999f, -2.0f), 2.0f);
    o.z = fminf(fmaxf(w.z * 0.999f, -2.0f), 2.0f);
    o.w = fminf(fmaxf(w.w * 0.999f, -2.0f), 2.0f);
    Wo[k] = o;
  }
  __shared__ float red[256];
  red[tid] = acc;
  __syncthreads();
  for (int s = 128; s; s >>= 1) {
    if (tid < s) red[tid] += red[tid + s];
    __syncthreads();
  }
  if (tid == 0) y[r] = red[0];
}

// ---------------------------------------------------------------------------
// K2: s_new = sigmoid(y + 0.05*normal(knoise))
// ---------------------------------------------------------------------------
__global__ __launch_bounds__(256) void k_snew(uint32_t kn0, uint32_t kn1,
                                              const float* __restrict__ y,
                                              float* __restrict__ s_new) {
#pragma clang fp contract(off)
  int i = blockIdx.x * 256 + threadIdx.x;
  if (i >= NN) return;
  uint32_t b0, b1;
  tf2x32(kn0, kn1, 0u, (uint32_t)i, b0, b1);
  float f = u01f(b0 ^ b1);
  const float lo = -0x1.fffffep-1f;              // nextafter(-1,0) in f32
  float u = f * 2.0f + lo;                        // (hi-lo) rounds to 2.0f
  u = fmaxf(lo, u);
  float ef = (float)erfinv((double)u);
  float nrm = 1.41421356237309515f * ef;          // sqrt(2) f32
  float noise = 0.05f * nrm;
  float x = y[i] + noise;
  double sg = 1.0 / (1.0 + exp(-(double)x));
  s_new[i] = (float)sg;
}

// K2b: sparks with age < 5 pin their node to 1.0
__global__ void k_forced(const int* __restrict__ sp, const int* __restrict__ age,
                         float* __restrict__ s_new) {
  int i = threadIdx.x;
  if (i < KK && age[i] < 5) s_new[sp[i]] = 1.0f;
}

// ---------------------------------------------------------------------------
// K3: per-spark explore flag, randint position, and kc_i keys
// ---------------------------------------------------------------------------
__global__ void k_sparkrng(uint32_t ke0, uint32_t ke1, uint32_t kr0, uint32_t kr1,
                           uint32_t kc0, uint32_t kc1,
                           int* __restrict__ explore, int* __restrict__ randpos,
                           uint32_t* __restrict__ kcA, uint32_t* __restrict__ kcB) {
  int i = threadIdx.x;
  if (i >= KK) return;
  // ke_i = tf(kexp, 0, i); uniform() scalar -> bits = w0^w1 of tf(ke_i,0,0)
  uint32_t a, b;
  tf2x32(ke0, ke1, 0u, (uint32_t)i, a, b);
  uint32_t e0, e1;
  tf2x32(a, b, 0u, 0u, e0, e1);
  explore[i] = (u01f(e0 ^ e1) < 0.05f) ? 1 : 0;
  // kr_i = tf(krand, 0, i); k2 = tf(kr_i,0,1); lower = bits(k2); pos = lower & 8191
  tf2x32(kr0, kr1, 0u, (uint32_t)i, a, b);
  uint32_t c0, c1;
  tf2x32(a, b, 0u, 1u, c0, c1);
  uint32_t l0, l1;
  tf2x32(c0, c1, 0u, 0u, l0, l1);
  randpos[i] = (int)((l0 ^ l1) & (uint32_t)(NN - 1));
  // kc_i = tf(kcat, 0, i)
  tf2x32(kc0, kc1, 0u, (uint32_t)i, a, b);
  kcA[i] = a; kcB[i] = b;
}

// ---------------------------------------------------------------------------
// K4: tables: g[j][c] = gumbel bits of (kc_j, c); rt[j][c] = (max(W[r_j,c],0)+1e-6)/0.3
// grid: 256 sparks * 32 blocks of 256 threads
// ---------------------------------------------------------------------------
__global__ __launch_bounds__(256) void k_tables(const uint32_t* __restrict__ kcA,
                                                const uint32_t* __restrict__ kcB,
                                                const int* __restrict__ sp,
                                                const float* __restrict__ W,
                                                float* __restrict__ g_tab,
                                                float* __restrict__ rt_tab) {
#pragma clang fp contract(off)
  int blk = blockIdx.x;
  int j = blk >> 5;
  int c = ((blk & 31) << 8) + threadIdx.x;
  uint32_t a = kcA[j], b = kcB[j];
  uint32_t o0, o1;
  tf2x32(a, b, 0u, (uint32_t)c, o0, o1);
  g_tab[(size_t)j * NN + c] = gumbelf(o0 ^ o1);
  int r = sp[j];
  float w = W[(size_t)r * NN + c];
  rt_tab[(size_t)j * NN + c] = (fmaxf(w, 0.0f) + 1e-6f) / 0.3f;
}

// ---------------------------------------------------------------------------
// K5: the sequential 256-iteration scan. Single workgroup, 1024 threads.
// ---------------------------------------------------------------------------
__global__ __launch_bounds__(1024) void k_scan(
    const float* __restrict__ W, const int* __restrict__ sp,
    const float* __restrict__ en_in, const int* __restrict__ age_in,
    const float* __restrict__ s_new, const int* __restrict__ explore,
    const int* __restrict__ randpos, const float* __restrict__ g_tab,
    const float* __restrict__ rt_tab, const float* __restrict__ M_in,
    float* __restrict__ out_pos, float* __restrict__ W_out,
    float* __restrict__ s_out, float* __restrict__ M_out,
    float* __restrict__ out_en, float* __restrict__ out_age) {
#pragma clang fp contract(off)
  __shared__ float s_lds[NN];
  __shared__ int upd_row[KK];
  __shared__ int upd_col[KK];
  __shared__ float upd_val[KK];
  __shared__ int ov_col[KK];
  __shared__ float ov_rt[KK];
  __shared__ unsigned long long ovmask[4];
  __shared__ float red_v[16];
  __shared__ int red_i[16];
  __shared__ float sh_posf[KK], sh_enf[KK], sh_agef[KK];
  __shared__ int sh_ovn, sh_nxt, sh_hasdup;

  int tid = threadIdx.x;
  int base = tid * 8;

  for (int k = tid; k < NN; k += 1024) s_lds[k] = s_new[k];
  float Mreg[8];
#pragma unroll
  for (int k = 0; k < 8; ++k) Mreg[k] = 0.95f * M_in[base + k];
  if (tid == 0) sh_hasdup = 0;
  __syncthreads();
  if (tid < KK) {
    int p = sp[tid];
    for (int u = 0; u < tid; ++u)
      if (sp[u] == p) sh_hasdup = 1;  // benign race: all write 1
  }
  // prefetch tables for j=0
  float gv[8], rv[8];
#pragma unroll
  for (int k = 0; k < 8; ++k) { gv[k] = g_tab[base + k]; rv[k] = rt_tab[base + k]; }
  __syncthreads();

  for (int j = 0; j < KK; ++j) {
    int prev = sp[j];
    int expl = explore[j];

    // --- phase 0: find earlier W-updates touching row `prev` (usually none) ---
    if (tid < KK) {
      bool m = (tid < j) && (upd_row[tid] == prev);
      unsigned long long msk = __ballot(m);
      if ((tid & 63) == 0) ovmask[tid >> 6] = msk;
    }
    __syncthreads();
    if (tid == 0) {
      int n = 0;
      for (int w = 0; w < 4; ++w) {
        unsigned long long m = ovmask[w];
        while (m) {
          int u = (w << 6) + __ffsll((unsigned long long)m) - 1;
          m &= m - 1;
          ov_col[n] = upd_col[u];
          ov_rt[n] = (fmaxf(upd_val[u], 0.0f) + 1e-6f) / 0.3f;
          ++n;
        }
      }
      sh_ovn = n;
    }
    __syncthreads();

    // --- phase 1: z = gumbel + (rowterm + 0.8*M), local then wave argmax ---
    float best = -3.4e38f;
    int bidx = 0x7FFFFFFF;
    if (!expl) {
      int ovn = sh_ovn;
#pragma unroll
      for (int k = 0; k < 8; ++k) {
        int c = base + k;
        float rt = rv[k];
        if (ovn) {
          for (int e = 0; e < ovn; ++e)
            if (ov_col[e] == c) rt = ov_rt[e];
        }
        float z = gv[k] + (rt + 0.8f * Mreg[k]);
        if (z > best) { best = z; bidx = c; }   // strict > keeps first index
      }
    }
    // prefetch next iteration's table slice (hidden under reduce+bookkeeping)
    if (j < KK - 1) {
      const float* gn = g_tab + (size_t)(j + 1) * NN + base;
      const float* rn = rt_tab + (size_t)(j + 1) * NN + base;
#pragma unroll
      for (int k = 0; k < 8; ++k) { gv[k] = gn[k]; rv[k] = rn[k]; }
    }
    if (!expl) {
#pragma unroll
      for (int off = 32; off >= 1; off >>= 1) {
        float ovv = __shfl_xor(best, off, 64);
        int ovi = __shfl_xor(bidx, off, 64);
        if (ovv > best || (ovv == best && ovi < bidx)) { best = ovv; bidx = ovi; }
      }
      if ((tid & 63) == 0) { red_v[tid >> 6] = best; red_i[tid >> 6] = bidx; }
    }
    __syncthreads();

    // --- phase 2: bookkeeping (thread 0) ---
    if (tid == 0) {
      int nxt;
      if (expl) {
        nxt = randpos[j];
      } else {
        float bv = red_v[0];
        int bi = red_i[0];
        for (int w = 1; w < 16; ++w) {
          float v = red_v[w];
          int ii = red_i[w];
          if (v > bv || (v == bv && ii < bi)) { bv = v; bi = ii; }
        }
        nxt = bi;
      }
      float oldW = W[(size_t)nxt * NN + prev];
      if (sh_hasdup) {
        for (int u = j - 1; u >= 0; --u)
          if (upd_row[u] == nxt && upd_col[u] == prev) { oldW = upd_val[u]; break; }
      }
      float s_prev = s_lds[prev];
      float newW = oldW * 0.95f + s_prev * 0.05f;   // (1-LR_EDGE), LR_EDGE
      upd_row[j] = nxt; upd_col[j] = prev; upd_val[j] = newW;
      float e = en_in[j] * 0.98f;
      s_lds[nxt] = e;
      int age = age_in[j] + 1;
      bool rs = e < 0.05f;
      sh_posf[j] = (float)(rs ? j : nxt);
      sh_enf[j] = rs ? 1.0f : e;
      sh_agef[j] = (float)(rs ? 0 : age);
      sh_nxt = nxt;
    }
    __syncthreads();
    int nx = sh_nxt;
    if ((nx >> 3) == tid) Mreg[nx & 7] += 0.2f;   // M deposit, owner thread
  }

  __syncthreads();
  // --- epilogue: write outputs ---
  for (int k = tid; k < NN; k += 1024) s_out[k] = s_lds[k];
#pragma unroll
  for (int k = 0; k < 8; ++k) M_out[base + k] = Mreg[k];
  if (tid < KK) {
    out_pos[tid] = sh_posf[tid];
    out_en[tid] = sh_enf[tid];
    out_age[tid] = sh_agef[tid];
  }
  if (tid == 0) {
    for (int u = 0; u < KK; ++u) {   // serial: preserves order for dup (r,c)
      float v = upd_val[u] * 0.999f;
      v = fminf(fmaxf(v, -2.0f), 2.0f);
      W_out[(size_t)upd_row[u] * NN + upd_col[u]] = v;
    }
  }
}

// ---------------------------------------------------------------------------
extern "C" void kernel_launch(void* const* d_in, const int* in_sizes, int n_in,
                              void* d_out, int out_size, void* d_ws, size_t ws_size,
                              hipStream_t stream) {
  (void)in_sizes; (void)n_in; (void)out_size; (void)ws_size;
  const float* W = (const float*)d_in[0];
  const float* s_in = (const float*)d_in[1];
  const float* M_in = (const float*)d_in[2];
  const int* sp = (const int*)d_in[3];
  const float* en_in = (const float*)d_in[4];
  const int* age_in = (const int*)d_in[5];

  float* out = (float*)d_out;
  float* out_pos = out;                       // 256
  float* W_out = out + KK;                    // 8192*8192
  float* s_out = W_out + (size_t)NN * NN;     // 8192
  float* M_out = s_out + NN;                  // 8192
  float* out_en = M_out + NN;                 // 256
  float* out_age = out_en + KK;               // 256

  float* ws = (float*)d_ws;
  float* y = ws;                              // 8192
  float* s_new = y + NN;                      // 8192
  int* explore = (int*)(s_new + NN);          // 256
  int* randpos = explore + KK;                // 256
  uint32_t* kcA = (uint32_t*)(randpos + KK);  // 256
  uint32_t* kcB = kcA + KK;                   // 256
  float* g_tab = (float*)(kcB + KK);          // 256*8192
  float* rt_tab = g_tab + (size_t)KK * NN;    // 256*8192

  // base keys: key(42) = (0,42); split(key,4) foldlike: tf(key, 0, i)
  uint32_t kn0, kn1, ke0, ke1, kr0, kr1, kc0, kc1;
  tf2x32(0u, 42u, 0u, 0u, kn0, kn1);  // knoise
  tf2x32(0u, 42u, 0u, 1u, ke0, ke1);  // kexp
  tf2x32(0u, 42u, 0u, 2u, kr0, kr1);  // krand
  tf2x32(0u, 42u, 0u, 3u, kc0, kc1);  // kcat

  k_matvec<<<NN, 256, 0, stream>>>(W, s_in, W_out, y);
  k_snew<<<NN / 256, 256, 0, stream>>>(kn0, kn1, y, s_new);
  k_forced<<<1, 256, 0, stream>>>(sp, age_in, s_new);
  k_sparkrng<<<1, 256, 0, stream>>>(ke0, ke1, kr0, kr1, kc0, kc1,
                                    explore, randpos, kcA, kcB);
  k_tables<<<KK * 32, 256, 0, stream>>>(kcA, kcB, sp, W, g_tab, rt_tab);
  k_scan<<<1, 1024, 0, stream>>>(W, sp, en_in, age_in, s_new, explore, randpos,
                                 g_tab, rt_tab, M_in, out_pos, W_out, s_out,
                                 M_out, out_en, out_age);
}